// Round 7
// baseline (333.807 us; speedup 1.0000x reference)
//
#include <hip/hip_runtime.h>
#include <hip/hip_bf16.h>

typedef unsigned short u16;
typedef __attribute__((ext_vector_type(8))) short short8;
typedef __attribute__((ext_vector_type(4))) float floatx4;

#define H 8
#define D 128
#define DIM 1024
#define QB 16
#define NSEQ 512
#define R 8192            /* QB*NSEQ rows */

__device__ inline u16 f2b(float x) {
    union { float f; unsigned int u; } c{x};
    unsigned int lsb = (c.u >> 16) & 1;
    unsigned int r = c.u + 0x7fffu + lsb;   // round-to-nearest-even
    return (u16)(r >> 16);
}
__device__ inline float b2f(u16 u) {
    union { unsigned int i; float f; } c;
    c.i = (unsigned int)u << 16;
    return c.f;
}

#define GLOAD_LDS16(gptr, lptr)                                                        \
    __builtin_amdgcn_global_load_lds(                                                  \
        (const __attribute__((address_space(1))) unsigned int*)(gptr),                 \
        (__attribute__((address_space(3))) unsigned int*)(lptr), 16, 0, 0)

// ---------------------------------------------------------------------------
// prep: fused weight-cast (blocks 0..2047) + LayerNorm q/k/v (blocks 2048..).
// LN: wave-per-row (16 elems/lane), pure shfl reduce -- no LDS, no barriers.
// ---------------------------------------------------------------------------
__global__ __launch_bounds__(256) void prep(const float* __restrict__ q,
                                            const float* __restrict__ k,
                                            const float* __restrict__ v,
                                            const float* __restrict__ g,
                                            const float* __restrict__ b,
                                            u16* __restrict__ out,
                                            const float* __restrict__ w_in,
                                            const float* __restrict__ w_out,
                                            u16* __restrict__ w_in16,
                                            u16* __restrict__ w_out16) {
    const int bb = blockIdx.x;
    const int tid = threadIdx.x;
    if (bb < 2048) {
        const int n4each = DIM * DIM / 4;
        int i = bb * 256 + tid;
        const float* src; u16* dst; int j;
        if (i < n4each) { src = w_in;  dst = w_in16;  j = i; }
        else            { src = w_out; dst = w_out16; j = i - n4each; }
        float4 vv = *(const float4*)(src + (size_t)j * 4);
        ushort4 pk;
        pk.x = f2b(vv.x); pk.y = f2b(vv.y); pk.z = f2b(vv.z); pk.w = f2b(vv.w);
        *(ushort4*)(dst + (size_t)j * 4) = pk;
        return;
    }
    const int b2 = bb - 2048;                    // 0..6143
    const int wv = tid >> 6, lane = tid & 63;
    const int row = b2 * 4 + wv;                 // 0..24575
    const int y = row >> 13, r = row & 8191;
    const float* src = (y == 0) ? q : (y == 1) ? k : v;
    const float* rp = src + (size_t)r * DIM;
    float4 x0 = *(const float4*)(rp + (0 * 64 + lane) * 4);
    float4 x1 = *(const float4*)(rp + (1 * 64 + lane) * 4);
    float4 x2 = *(const float4*)(rp + (2 * 64 + lane) * 4);
    float4 x3 = *(const float4*)(rp + (3 * 64 + lane) * 4);
    float sum = (x0.x + x0.y + x0.z + x0.w) + (x1.x + x1.y + x1.z + x1.w)
              + (x2.x + x2.y + x2.z + x2.w) + (x3.x + x3.y + x3.z + x3.w);
    float sq = x0.x*x0.x + x0.y*x0.y + x0.z*x0.z + x0.w*x0.w
             + x1.x*x1.x + x1.y*x1.y + x1.z*x1.z + x1.w*x1.w
             + x2.x*x2.x + x2.y*x2.y + x2.z*x2.z + x2.w*x2.w
             + x3.x*x3.x + x3.y*x3.y + x3.z*x3.z + x3.w*x3.w;
#pragma unroll
    for (int o = 32; o > 0; o >>= 1) {
        sum += __shfl_xor(sum, o);
        sq  += __shfl_xor(sq, o);
    }
    float mean = sum * (1.0f / DIM);
    float var = sq * (1.0f / DIM) - mean * mean;
    float rstd = rsqrtf(var + 1e-5f);
    u16* op = out + ((size_t)y * R + r) * DIM;
    float4 xs[4] = {x0, x1, x2, x3};
#pragma unroll
    for (int p = 0; p < 4; p++) {
        int e4 = (p * 64 + lane) * 4;
        float4 gv = *(const float4*)(g + e4);
        float4 bv = *(const float4*)(b + e4);
        ushort4 pk;
        pk.x = f2b((xs[p].x - mean) * rstd * gv.x + bv.x);
        pk.y = f2b((xs[p].y - mean) * rstd * gv.y + bv.y);
        pk.z = f2b((xs[p].z - mean) * rstd * gv.z + bv.z);
        pk.w = f2b((xs[p].w - mean) * rstd * gv.w + bv.w);
        *(ushort4*)(op + e4) = pk;
    }
}

// ---------------------------------------------------------------------------
// Stacked QKV projection, operand-SWAPPED MFMA, BK=64.  (verbatim, proven)
// ---------------------------------------------------------------------------
__global__ __launch_bounds__(256) void gemm_qkv(const u16* __restrict__ A,
                                                const u16* __restrict__ B,
                                                u16* __restrict__ qT,
                                                u16* __restrict__ fqb,
                                                u16* __restrict__ kTh,
                                                u16* __restrict__ vT,
                                                float* __restrict__ qn,
                                                float* __restrict__ qm,
                                                float* __restrict__ qr,
                                                float* __restrict__ kn,
                                                float* __restrict__ kr) {
    __shared__ __align__(16) u16 smem[19712];
    u16* As  = smem;                             // 4096 u16 (k lo)
    u16* Bs  = smem + 4096;                      // 4096 u16 (k lo)
    u16* As2 = smem + 8192;                      // 4096 u16 (k hi)
    u16* Bs2 = smem + 12288;                     // 4096 u16 (k hi)
    float* sred = (float*)(smem + 18432);        // 128*4 floats
    float* invb = (float*)(smem + 19456);        // 128 floats

    const int tid = threadIdx.x;
    const int bb = blockIdx.x;
    const int xcd = bb & 7, j0 = bb >> 3;
    const int h = j0 & 7;                        // column block (head)
    const int rowblk = xcd * 24 + (j0 >> 3);     // 0..191
    const int m0 = rowblk * 128, n0 = h * 128;
    const int seg = rowblk >> 6;                 // 0=Q 1=K 2=V
    const int lrb = (rowblk & 63) * 128;         // segment-local row base

    const int wave = tid >> 6, lane = tid & 63;
    const int wm = (wave >> 1) * 64, wn = (wave & 1) * 64;
    const int fr = lane & 15, kq = lane >> 4;
    const int srow = tid >> 2, scol = (tid & 3) * 8;

    floatx4 acc[4][4] = {};                      // [j=c-tile][i=r-tile]
    const size_t aOff0 = (size_t)(m0 + srow) * DIM + scol;
    const size_t aOff1 = (size_t)(m0 + 64 + srow) * DIM + scol;
    const size_t bOff0 = (size_t)(n0 + srow) * DIM + scol;
    const size_t bOff1 = (size_t)(n0 + 64 + srow) * DIM + scol;

    for (int kt = 0; kt < DIM; kt += 64) {
        GLOAD_LDS16(A + aOff0 + kt, As + tid * 8);
        GLOAD_LDS16(A + aOff1 + kt, As + (256 + tid) * 8);
        GLOAD_LDS16(B + bOff0 + kt, Bs + tid * 8);
        GLOAD_LDS16(B + bOff1 + kt, Bs + (256 + tid) * 8);
        GLOAD_LDS16(A + aOff0 + kt + 32, As2 + tid * 8);
        GLOAD_LDS16(A + aOff1 + kt + 32, As2 + (256 + tid) * 8);
        GLOAD_LDS16(B + bOff0 + kt + 32, Bs2 + tid * 8);
        GLOAD_LDS16(B + bOff1 + kt + 32, Bs2 + (256 + tid) * 8);
        __syncthreads();
        short8 xf[4], wf[4];
#pragma unroll
        for (int i = 0; i < 4; i++)
            xf[i] = *(const short8*)&As[(wm + i * 16 + fr) * 32 + kq * 8];
#pragma unroll
        for (int j = 0; j < 4; j++)
            wf[j] = *(const short8*)&Bs[(wn + j * 16 + fr) * 32 + kq * 8];
#pragma unroll
        for (int j = 0; j < 4; j++)
#pragma unroll
            for (int i = 0; i < 4; i++)
                acc[j][i] = __builtin_amdgcn_mfma_f32_16x16x32_bf16(wf[j], xf[i], acc[j][i], 0, 0, 0);
        short8 xg[4], wg[4];
#pragma unroll
        for (int i = 0; i < 4; i++)
            xg[i] = *(const short8*)&As2[(wm + i * 16 + fr) * 32 + kq * 8];
#pragma unroll
        for (int j = 0; j < 4; j++)
            wg[j] = *(const short8*)&Bs2[(wn + j * 16 + fr) * 32 + kq * 8];
#pragma unroll
        for (int j = 0; j < 4; j++)
#pragma unroll
            for (int i = 0; i < 4; i++)
                acc[j][i] = __builtin_amdgcn_mfma_f32_16x16x32_bf16(wg[j], xg[i], acc[j][i], 0, 0, 0);
        __syncthreads();
    }

    if (seg <= 1) {
        const int half = wn >> 6;
#pragma unroll
        for (int i = 0; i < 4; i++) {
            float s = 0.0f, qs = 0.0f;
#pragma unroll
            for (int j = 0; j < 4; j++)
#pragma unroll
                for (int rg = 0; rg < 4; rg++) {
                    float vv = acc[j][i][rg];
                    s += vv; qs += vv * vv;
                }
            s += __shfl_xor(s, 16); qs += __shfl_xor(qs, 16);
            s += __shfl_xor(s, 32); qs += __shfl_xor(qs, 32);
            if (kq == 0) {
                int rl = wm + i * 16 + fr;
                sred[rl * 4 + half * 2 + 0] = s;
                sred[rl * 4 + half * 2 + 1] = qs;
            }
        }
        __syncthreads();
        if (tid < 128) {
            float sum = sred[tid * 4 + 0] + sred[tid * 4 + 2];
            float sq  = sred[tid * 4 + 1] + sred[tid * 4 + 3];
            float nrm = sqrtf(sq);
            float var = (sq - sum * sum * (1.0f / D)) * (1.0f / (D - 1));
            float ratio = 2.0f * fminf(var, 1.0f) / (var + 1.0f);
            size_t idx = (size_t)h * R + lrb + tid;
            if (seg == 0) {
                qn[idx] = nrm; qm[idx] = sum * (1.0f / D); qr[idx] = ratio;
            } else {
                kn[idx] = nrm; kr[idx] = ratio;
                invb[tid] = 1.0f / nrm;
            }
        }
        __syncthreads();
    }

    u16* dstT = (seg == 0) ? qT : (seg == 1) ? kTh : vT;
#pragma unroll
    for (int i = 0; i < 4; i++) {
        const int rl = wm + i * 16 + fr;
        const float sc = (seg == 1) ? invb[rl] : 1.0f;
#pragma unroll
        for (int j = 0; j < 4; j++) {
#pragma unroll
            for (int rg = 0; rg < 4; rg++) {
                const int cl = wn + j * 16 + kq * 4 + rg;
                dstT[(size_t)(h * D + cl) * R + lrb + rl] = f2b(acc[j][i][rg] * sc);
            }
        }
    }

    if (seg == 0) {
        __syncthreads();
        u16* Tw = smem + wave * 4608;            // 64 x 72 u16
#pragma unroll
        for (int i = 0; i < 4; i++)
#pragma unroll
            for (int j = 0; j < 4; j++) {
                ushort4 pk;
                pk.x = f2b(acc[j][i][0]); pk.y = f2b(acc[j][i][1]);
                pk.z = f2b(acc[j][i][2]); pk.w = f2b(acc[j][i][3]);
                *(ushort4*)&Tw[(i * 16 + fr) * 72 + j * 16 + kq * 4] = pk;
            }
        __syncthreads();
#pragma unroll
        for (int p = 0; p < 16; p++) {
            int rloc = p * 4 + kq;
            int c4 = fr * 4;
            ushort4 v = *(const ushort4*)&Tw[rloc * 72 + c4];
            *(ushort4*)&fqb[(size_t)(lrb + wm + rloc) * DIM + h * D + wn + c4] = v;
        }
    }
}

// ---------------------------------------------------------------------------
// fanout: fused  ktv_mfma (blocks 0..127, BK=64)  |  syrk_q (128..191, BK=64)
//         |  colsum2 (192..447).  (verbatim, proven in R5)
// ---------------------------------------------------------------------------
__global__ __launch_bounds__(256) void fanout(const u16* __restrict__ qT,
                                              const u16* __restrict__ kTh,
                                              const u16* __restrict__ vT,
                                              const float* __restrict__ qm,
                                              const float* __restrict__ kn,
                                              const float* __restrict__ kr,
                                              float* __restrict__ qg,
                                              float* __restrict__ kg,
                                              float* __restrict__ ubuf,
                                              float* __restrict__ s2,
                                              float* __restrict__ P,
                                              u16* __restrict__ Mt,
                                              float* __restrict__ sv) {
    __shared__ __align__(16) u16 sm[17040];      // 34080 B
    u16* As = sm;                                // 8192 u16 (2 chunks x 4096)
    u16* Bs = sm + 8192;                         // 8192 u16
    float* wbuf  = (float*)(sm + 16384);         // 64 floats
    float* svred = (float*)(sm + 16512);         // 256 floats
    float* redS  = (float*)(sm + 17024);         // 8 floats

    const int bb = blockIdx.x;
    const int tid = threadIdx.x;
    const int wave = tid >> 6, lane = tid & 63;
    const int wm = (wave >> 1) * 64, wn = (wave & 1) * 64;
    const int fr = lane & 15, kq = lane >> 4;
    const int srow = tid >> 2, scol = (tid & 3) * 8;

    if (bb < 128) {
        const int qi = bb & 15, h = bb >> 4;
        const int m0g = qi * 512;
        const size_t a0 = (size_t)(h * D + srow) * R + m0g + scol;
        const size_t a1 = (size_t)(h * D + 64 + srow) * R + m0g + scol;
        const int e_id = tid & 127, mb16 = (tid >> 7) * 16;
        float svacc = 0.0f;
        floatx4 acc[4][4] = {};
        for (int kt = 0; kt < 512; kt += 64) {
#pragma unroll
            for (int kc = 0; kc < 2; kc++) {
                GLOAD_LDS16(vT + a0 + kt + kc * 32, As + kc * 4096 + tid * 8);
                GLOAD_LDS16(vT + a1 + kt + kc * 32, As + kc * 4096 + (256 + tid) * 8);
                GLOAD_LDS16(kTh + a0 + kt + kc * 32, Bs + kc * 4096 + tid * 8);
                GLOAD_LDS16(kTh + a1 + kt + kc * 32, Bs + kc * 4096 + (256 + tid) * 8);
            }
            if (tid < 64) wbuf[tid] = kr[(size_t)h * R + m0g + kt + tid];
            __syncthreads();
#pragma unroll
            for (int kc = 0; kc < 2; kc++) {
                short8 af[4], bf[4];
#pragma unroll
                for (int i = 0; i < 4; i++)
                    af[i] = *(const short8*)&As[kc * 4096 + (wm + i * 16 + fr) * 32 + kq * 8];
#pragma unroll
                for (int j = 0; j < 4; j++)
                    bf[j] = *(const short8*)&Bs[kc * 4096 + (wn + j * 16 + fr) * 32 + kq * 8];
#pragma unroll
                for (int i = 0; i < 4; i++)
#pragma unroll
                    for (int j = 0; j < 4; j++)
                        acc[i][j] = __builtin_amdgcn_mfma_f32_16x16x32_bf16(af[i], bf[j], acc[i][j], 0, 0, 0);
                short8 va = *(const short8*)&As[kc * 4096 + e_id * 32 + mb16];
                short8 vb = *(const short8*)&As[kc * 4096 + e_id * 32 + mb16 + 8];
#pragma unroll
                for (int jm = 0; jm < 8; jm++)
                    svacc += b2f((u16)va[jm]) * wbuf[kc * 32 + mb16 + jm];
#pragma unroll
                for (int jm = 0; jm < 8; jm++)
                    svacc += b2f((u16)vb[jm]) * wbuf[kc * 32 + mb16 + 8 + jm];
            }
            __syncthreads();
        }
        u16* mb = Mt + (size_t)(h * QB + qi) * D * D;
#pragma unroll
        for (int i = 0; i < 4; i++) {
            int er = wm + i * 16 + kq * 4;
#pragma unroll
            for (int j = 0; j < 4; j++) {
                int dc = wn + j * 16 + fr;
#pragma unroll
                for (int r = 0; r < 4; r++)
                    mb[(size_t)(er + r) * D + dc] = f2b(acc[i][j][r]);
            }
        }
        svred[tid] = svacc;
        __syncthreads();
        if (tid < 128)
            sv[(size_t)(h * QB + qi) * D + tid] = svred[tid] + svred[tid + 128];
    } else if (bb < 192) {
        const int t = bb - 128;
        const int c = t & 7, h = t >> 3;
        floatx4 acc[4][4] = {};
        const size_t a0 = (size_t)(h * D + srow) * R + c * 1024 + scol;
        const size_t a1 = (size_t)(h * D + 64 + srow) * R + c * 1024 + scol;
        for (int kt = 0; kt < 1024; kt += 64) {
#pragma unroll
            for (int kc = 0; kc < 2; kc++) {
                GLOAD_LDS16(qT + a0 + kt + kc * 32, As + kc * 4096 + tid * 8);
                GLOAD_LDS16(qT + a1 + kt + kc * 32, As + kc * 4096 + (256 + tid) * 8);
            }
            __syncthreads();
#pragma unroll
            for (int kc = 0; kc < 2; kc++) {
                short8 af[4], bf[4];
#pragma unroll
                for (int i = 0; i < 4; i++)
                    af[i] = *(const short8*)&As[kc * 4096 + (wm + i * 16 + fr) * 32 + kq * 8];
#pragma unroll
                for (int j = 0; j < 4; j++)
                    bf[j] = *(const short8*)&As[kc * 4096 + (wn + j * 16 + fr) * 32 + kq * 8];
#pragma unroll
                for (int i = 0; i < 4; i++)
#pragma unroll
                    for (int j = 0; j < 4; j++)
                        acc[i][j] = __builtin_amdgcn_mfma_f32_16x16x32_bf16(af[i], bf[j], acc[i][j], 0, 0, 0);
            }
            __syncthreads();
        }
        float* base = P + (size_t)(h * 8 + c) * (D * D);
#pragma unroll
        for (int i = 0; i < 4; i++) {
            int dr = wm + i * 16 + kq * 4;
#pragma unroll
            for (int j = 0; j < 4; j++) {
                int ec = wn + j * 16 + fr;
                float4 f4;
                f4.x = acc[i][j][0]; f4.y = acc[i][j][1];
                f4.z = acc[i][j][2]; f4.w = acc[i][j][3];
                *(float4*)&base[(size_t)ec * D + dr] = f4;   // symmetric chunk
            }
        }
    } else {
        const int t = bb - 192;
        const int dg = t & 15, h = (t >> 4) & 7, mode = t >> 7;
        const u16* fT = mode ? kTh : qT;
        const float* wvec = mode ? kn : qm;
        const int wv = tid >> 6;
        float (*red)[4] = (float(*)[4])redS;
        const float* wp = wvec + (size_t)h * R;
        for (int dd = 0; dd < 8; dd++) {
            int d = dg * 8 + dd;
            const u16* rowp = fT + (size_t)(h * D + d) * R;
            float s = 0.0f, su = 0.0f;
            for (int it = 0; it < 8; it++) {
                int r = it * 1024 + tid * 4;
                uint2 pv = *(const uint2*)(rowp + r);
                float4 w = *(const float4*)(wp + r);
                float v0 = b2f((u16)(pv.x & 0xffffu)), v1 = b2f((u16)(pv.x >> 16));
                float v2 = b2f((u16)(pv.y & 0xffffu)), v3 = b2f((u16)(pv.y >> 16));
                if (mode) s += v0 * w.x + v1 * w.y + v2 * w.z + v3 * w.w;
                else {
                    s += v0 + v1 + v2 + v3;
                    su += v0 * w.x + v1 * w.y + v2 * w.z + v3 * w.w;
                }
            }
#pragma unroll
            for (int o = 32; o > 0; o >>= 1) {
                s += __shfl_xor(s, o);
                su += __shfl_xor(su, o);
            }
            if ((tid & 63) == 0) { red[0][wv] = s; red[1][wv] = su; }
            __syncthreads();
            if (tid == 0) {
                float S  = red[0][0] + red[0][1] + red[0][2] + red[0][3];
                float SU = red[1][0] + red[1][1] + red[1][2] + red[1][3];
                if (mode) kg[h * D + d] = S * (1.0f / R);
                else { qg[h * D + d] = S * (1.0f / R); ubuf[h * D + d] = SU; }
            }
            __syncthreads();
        }
        if (!mode && dg == 0) {
            float tt = 0.0f;
            for (int it = 0; it < 8; it++) {
                float4 m4 = *(const float4*)(qm + (size_t)h * R + it * 1024 + tid * 4);
                tt += m4.x * m4.x + m4.y * m4.y + m4.z * m4.z + m4.w * m4.w;
            }
#pragma unroll
            for (int o = 32; o > 0; o >>= 1) tt += __shfl_xor(tt, o);
            if ((tid & 63) == 0) red[0][wv] = tt;
            __syncthreads();
            if (tid == 0) s2[h] = red[0][0] + red[0][1] + red[0][2] + red[0][3];
        }
    }
}

// ---------------------------------------------------------------------------
// attn2: inline decorr-sum (P is L2-resident) + inline predictor MLP per
// block (redundant per head, removes decorr_sum + head_kernel dispatches),
// then one-shot K=128 MFMA.  Staging loads issued FIRST so HBM latency
// hides under the decorr/head compute.
// ---------------------------------------------------------------------------
__global__ __launch_bounds__(256) void attn2(const u16* __restrict__ fqb,
                                             const u16* __restrict__ Mt,
                                             const float* __restrict__ qn,
                                             const float* __restrict__ qr,
                                             const float* __restrict__ sv,
                                             const float* __restrict__ P,
                                             const float* __restrict__ ubuf,
                                             const float* __restrict__ s2b,
                                             const float* __restrict__ qg,
                                             const float* __restrict__ kg,
                                             const float* __restrict__ w1,
                                             const float* __restrict__ b1,
                                             const float* __restrict__ lng,
                                             const float* __restrict__ lnb,
                                             const float* __restrict__ w2,
                                             const float* __restrict__ b2,
                                             u16* __restrict__ outb) {
    __shared__ u16 As[128 * 128];    // 32 KB: 4 chunks of [128][32]
    __shared__ u16 Bs[128 * 128];    // 32 KB
    __shared__ float hscratch[1024]; // 4 KB: head MLP / reductions
    const int nb = blockIdx.x, qi = blockIdx.y, h = blockIdx.z;
    const int tid = threadIdx.x;
    const int wave = tid >> 6, lane = tid & 63;
    const int wm = (wave >> 1) * 64, wn = (wave & 1) * 64;
    const int fr = lane & 15, kq = lane >> 4;
    const int srow = tid >> 2, scol = (tid & 3) * 8;
    const int n0g = qi * 512 + nb * 128;
    const size_t a0 = (size_t)(n0g + srow) * DIM + h * D + scol;
    const size_t a1 = (size_t)(n0g + 64 + srow) * DIM + h * D + scol;
    const u16* mtb = Mt + (size_t)(h * QB + qi) * D * D;

    // ---- issue all staging loads up front (latency hides under head calc)
#pragma unroll
    for (int kc = 0; kc < 4; kc++) {
        GLOAD_LDS16(fqb + a0 + kc * 32, As + kc * 4096 + tid * 8);
        GLOAD_LDS16(fqb + a1 + kc * 32, As + kc * 4096 + (256 + tid) * 8);
        GLOAD_LDS16(mtb + (size_t)srow * D + kc * 32 + scol, Bs + kc * 4096 + tid * 8);
        GLOAD_LDS16(mtb + (size_t)(64 + srow) * D + kc * 32 + scol, Bs + kc * 4096 + (256 + tid) * 8);
    }

    // ---- inline decorr: Ssum over this head's centered off-diag Gram
    float c0, c1;
    {
        float s2h = s2b[h];
        float part = 0.0f;
        for (int k = 0; k < 64; k++) {
            int de = k * 256 + tid;              // 0..16383
            int dd = de >> 7, ee = de & 127;
            float gsum = 0.0f;
#pragma unroll
            for (int c = 0; c < 8; c++)
                gsum += P[(size_t)(h * 8 + c) * (D * D) + de];
            if (dd != ee) {
                float vv = (gsum - ubuf[h * D + dd] - ubuf[h * D + ee] + s2h) * (1.0f / R);
                part += vv * vv;
            }
        }
#pragma unroll
        for (int o = 32; o > 0; o >>= 1) part += __shfl_xor(part, o);
        if (lane == 0) hscratch[wave] = part;
        __syncthreads();
        float Ssum = hscratch[0] + hscratch[1] + hscratch[2] + hscratch[3];
        float dscale = expf(-5.0f * sqrtf(Ssum) / (float)(D * D));
        __syncthreads();

        // ---- inline head MLP (verbatim head_kernel arithmetic)
        float* hs1 = hscratch;
        float* hs2 = hscratch + 256;
        float* hs3 = hscratch + 512;
        float* hfe = hscratch + 768;
        hfe[tid] = (tid < 128) ? qg[h * D + tid] : kg[h * D + tid - 128];
        __syncthreads();
        float yv = 0.0f;
        if (tid < 128) {
            float a = b1[tid];
            for (int i = 0; i < 256; i++) a = fmaf(hfe[i], w1[tid * 256 + i], a);
            yv = a;
        }
        hs1[tid] = (tid < 128) ? yv : 0.0f;
        hs2[tid] = (tid < 128) ? yv * yv : 0.0f;
        __syncthreads();
        for (int s = 128; s > 0; s >>= 1) {
            if (tid < s) { hs1[tid] += hs1[tid + s]; hs2[tid] += hs2[tid + s]; }
            __syncthreads();
        }
        float mean = hs1[0] * (1.0f / 128.0f);
        float var = hs2[0] * (1.0f / 128.0f) - mean * mean;
        float rstd = rsqrtf(var + 1e-5f);
        float rel = 0.0f;
        if (tid < 128)
            rel = fmaxf((yv - mean) * rstd * lng[tid] + lnb[tid], 0.0f);
        __syncthreads();
        hs1[tid] = (tid < 128) ? rel * w2[0 * 128 + tid] : 0.0f;
        hs2[tid] = (tid < 128) ? rel * w2[1 * 128 + tid] : 0.0f;
        hs3[tid] = (tid < 128) ? rel * w2[2 * 128 + tid] : 0.0f;
        __syncthreads();
        for (int s = 128; s > 0; s >>= 1) {
            if (tid < s) { hs1[tid] += hs1[tid + s]; hs2[tid] += hs2[tid + s]; hs3[tid] += hs3[tid + s]; }
            __syncthreads();
        }
        if (tid == 0) {
            float g0 = hs1[0] + b2[0], g1 = hs2[0] + b2[1], g2 = hs3[0] + b2[2];
            float mx = fmaxf(g0, fmaxf(g1, g2));
            float e0 = expf(g0 - mx), e1 = expf(g1 - mx), e2 = expf(g2 - mx);
            float inv = 1.0f / (e0 + e1 + e2);
            hs1[0] = e0 * inv + e1 * inv * dscale;   // cw + vw*dscale
            hs1[1] = e2 * inv;                       // ww
        }
        __syncthreads();
        c0 = hs1[0]; c1 = hs1[1];
    }

    // ---- ensure staging complete (barriers above drain, this is belt+braces)
    asm volatile("s_waitcnt vmcnt(0)" ::: "memory");
    __syncthreads();

    floatx4 acc[4][4] = {};
#pragma unroll
    for (int kc = 0; kc < 4; kc++) {
        short8 af[4], bf[4];
#pragma unroll
        for (int i = 0; i < 4; i++)
            af[i] = *(const short8*)&As[kc * 4096 + (wm + i * 16 + fr) * 32 + kq * 8];
#pragma unroll
        for (int j = 0; j < 4; j++)
            bf[j] = *(const short8*)&Bs[kc * 4096 + (wn + j * 16 + fr) * 32 + kq * 8];
#pragma unroll
        for (int i = 0; i < 4; i++)
#pragma unroll
            for (int j = 0; j < 4; j++)
                acc[i][j] = __builtin_amdgcn_mfma_f32_16x16x32_bf16(af[i], bf[j], acc[i][j], 0, 0, 0);
    }
#pragma unroll
    for (int i = 0; i < 4; i++) {
        int nr = n0g + wm + i * 16 + kq * 4;
        float4 nv = *(const float4*)&qn[(size_t)h * R + nr];
        float4 rv = *(const float4*)&qr[(size_t)h * R + nr];
        float sc1[4] = {c0 / nv.x, c0 / nv.y, c0 / nv.z, c0 / nv.w};
        float sc2[4] = {c1 * rv.x, c1 * rv.y, c1 * rv.z, c1 * rv.w};
#pragma unroll
        for (int j = 0; j < 4; j++) {
            int ec = wn + j * 16 + fr;
            float svv = sv[(size_t)(h * QB + qi) * D + ec];
#pragma unroll
            for (int r = 0; r < 4; r++)
                outb[(size_t)(nr + r) * DIM + h * D + ec] = f2b(sc1[r] * acc[i][j][r] + sc2[r] * svv);
        }
    }
}

// ---------------------------------------------------------------------------
// Output GEMM, 1-D grid 512 with XCD swizzle, BK=64.  (verbatim, proven)
// ---------------------------------------------------------------------------
__global__ __launch_bounds__(256) void gemm_out(const u16* __restrict__ A,
                                                const u16* __restrict__ B,
                                                const float* __restrict__ bias,
                                                float* __restrict__ C) {
    __shared__ u16 As[128 * 64];
    __shared__ u16 Bs[128 * 64];
    const int tid = threadIdx.x;
    const int bb = blockIdx.x;
    const int xcd = bb & 7, jj = bb >> 3;
    const int col = jj & 7, rowblk = xcd * 8 + (jj >> 3);
    const int m0 = rowblk * 128, n0 = col * 128;
    const int wave = tid >> 6, lane = tid & 63;
    const int wm = (wave >> 1) * 64, wn = (wave & 1) * 64;
    const int fr = lane & 15, kq = lane >> 4;
    const int srow = tid >> 2, scol = (tid & 3) * 8;
    floatx4 acc[4][4] = {};
    const size_t aOff0 = (size_t)(m0 + srow) * DIM + scol;
    const size_t aOff1 = (size_t)(m0 + 64 + srow) * DIM + scol;
    const size_t bOff0 = (size_t)(n0 + srow) * DIM + scol;
    const size_t bOff1 = (size_t)(n0 + 64 + srow) * DIM + scol;
    for (int kt = 0; kt < DIM; kt += 64) {
        GLOAD_LDS16(A + aOff0 + kt, As + tid * 8);
        GLOAD_LDS16(A + aOff1 + kt, As + (256 + tid) * 8);
        GLOAD_LDS16(A + aOff0 + kt + 32, As + (512 + tid) * 8);
        GLOAD_LDS16(A + aOff1 + kt + 32, As + (768 + tid) * 8);
        GLOAD_LDS16(B + bOff0 + kt, Bs + tid * 8);
        GLOAD_LDS16(B + bOff1 + kt, Bs + (256 + tid) * 8);
        GLOAD_LDS16(B + bOff0 + kt + 32, Bs + (512 + tid) * 8);
        GLOAD_LDS16(B + bOff1 + kt + 32, Bs + (768 + tid) * 8);
        __syncthreads();
        short8 af[4], bf[4];
#pragma unroll
        for (int i = 0; i < 4; i++)
            af[i] = *(const short8*)&As[(wm + i * 16 + fr) * 32 + kq * 8];
#pragma unroll
        for (int j = 0; j < 4; j++)
            bf[j] = *(const short8*)&Bs[(wn + j * 16 + fr) * 32 + kq * 8];
#pragma unroll
        for (int i = 0; i < 4; i++)
#pragma unroll
            for (int j = 0; j < 4; j++)
                acc[i][j] = __builtin_amdgcn_mfma_f32_16x16x32_bf16(af[i], bf[j], acc[i][j], 0, 0, 0);
        short8 ag[4], bg[4];
#pragma unroll
        for (int i = 0; i < 4; i++)
            ag[i] = *(const short8*)&As[4096 + (wm + i * 16 + fr) * 32 + kq * 8];
#pragma unroll
        for (int j = 0; j < 4; j++)
            bg[j] = *(const short8*)&Bs[4096 + (wn + j * 16 + fr) * 32 + kq * 8];
#pragma unroll
        for (int i = 0; i < 4; i++)
#pragma unroll
            for (int j = 0; j < 4; j++)
                acc[i][j] = __builtin_amdgcn_mfma_f32_16x16x32_bf16(ag[i], bg[j], acc[i][j], 0, 0, 0);
        __syncthreads();
    }
#pragma unroll
    for (int i = 0; i < 4; i++) {
        int rbase = m0 + wm + i * 16 + kq * 4;
#pragma unroll
        for (int j = 0; j < 4; j++) {
            int c = n0 + wn + j * 16 + fr;
            float badd = bias[c];
#pragma unroll
            for (int r = 0; r < 4; r++)
                C[(size_t)(rbase + r) * DIM + c] = acc[i][j][r] + badd;
        }
    }
}

// ---------------------------------------------------------------------------
extern "C" void kernel_launch(void* const* d_in, const int* in_sizes, int n_in,
                              void* d_out, int out_size, void* d_ws, size_t ws_size,
                              hipStream_t stream) {
    (void)in_sizes; (void)n_in; (void)out_size; (void)ws_size;
    const float* q      = (const float*)d_in[0];
    const float* k      = (const float*)d_in[1];
    const float* v      = (const float*)d_in[2];
    const float* ln_g   = (const float*)d_in[3];
    const float* ln_b   = (const float*)d_in[4];
    const float* w_in   = (const float*)d_in[5];
    const float* wp_w1  = (const float*)d_in[6];
    const float* wp_b1  = (const float*)d_in[7];
    const float* wp_lng = (const float*)d_in[8];
    const float* wp_lnb = (const float*)d_in[9];
    const float* wp_w2  = (const float*)d_in[10];
    const float* wp_b2  = (const float*)d_in[11];
    const float* w_out  = (const float*)d_in[12];
    const float* b_out  = (const float*)d_in[13];
    float* out = (float*)d_out;

    constexpr size_t F = (size_t)R * DIM;     // 8,388,608 elements
    u16* lnall   = (u16*)d_ws;                // 3F (LN out; first F reused as attn out)
    u16* fqb     = lnall + 3 * F;             // f_q row-major bf16
    u16* qT      = fqb + F;                   // [h][d][r]
    u16* kTh     = qT + F;                    // K/||k||
    u16* vT      = kTh + F;                   // V (plain)
    u16* w_in16  = vT + F;
    u16* w_out16 = w_in16 + (size_t)DIM * DIM;
    u16* Mt      = w_out16 + (size_t)DIM * DIM;       // H*QB*D*D
    float* P     = (float*)(Mt + (size_t)H * QB * D * D);  // 8*H*D*D fp32 used
    float* qn    = P + (size_t)32 * H * D * D;
    float* qm    = qn + (size_t)H * R;
    float* qr    = qm + (size_t)H * R;
    float* kn    = qr + (size_t)H * R;
    float* kr    = kn + (size_t)H * R;
    float* qg    = kr + (size_t)H * R;        // H*D
    float* kg    = qg + H * D;
    float* ubuf  = kg + H * D;
    float* s2    = ubuf + H * D;              // H
    float* Spart = s2 + H;                    // (legacy slot, unused)
    float* coef  = Spart + H * 8;             // (legacy slot, unused)
    float* svb   = coef + 16;                 // H*QB*D

    prep<<<8192, 256, 0, stream>>>(q, k, v, ln_g, ln_b, lnall,
                                   w_in, w_out, w_in16, w_out16);

    gemm_qkv<<<1536, 256, 0, stream>>>(lnall, w_in16, qT, fqb, kTh, vT,
                                       qn, qm, qr, kn, kr);

    fanout<<<448, 256, 0, stream>>>(qT, kTh, vT, qm, kn, kr,
                                    qg, kg, ubuf, s2, P, Mt, svb);

    attn2<<<dim3(4, QB, H), 256, 0, stream>>>(fqb, Mt, qn, qr, svb,
                                              P, ubuf, s2, qg, kg,
                                              wp_w1, wp_b1, wp_lng, wp_lnb,
                                              wp_w2, wp_b2, lnall);

    gemm_out<<<512, 256, 0, stream>>>(lnall, w_out16, b_out, out);
}

// Round 9
// 313.511 us; speedup vs baseline: 1.0647x; 1.0647x over previous
//
#include <hip/hip_runtime.h>
#include <hip/hip_bf16.h>

typedef unsigned short u16;
typedef __attribute__((ext_vector_type(8))) short short8;
typedef __attribute__((ext_vector_type(4))) float floatx4;

#define H 8
#define D 128
#define DIM 1024
#define QB 16
#define NSEQ 512
#define R 8192            /* QB*NSEQ rows */

__device__ inline u16 f2b(float x) {
    union { float f; unsigned int u; } c{x};
    unsigned int lsb = (c.u >> 16) & 1;
    unsigned int r = c.u + 0x7fffu + lsb;   // round-to-nearest-even
    return (u16)(r >> 16);
}
__device__ inline float b2f(u16 u) {
    union { unsigned int i; float f; } c;
    c.i = (unsigned int)u << 16;
    return c.f;
}

#define GLOAD_LDS16(gptr, lptr)                                                        \
    __builtin_amdgcn_global_load_lds(                                                  \
        (const __attribute__((address_space(1))) unsigned int*)(gptr),                 \
        (__attribute__((address_space(3))) unsigned int*)(lptr), 16, 0, 0)

// ---------------------------------------------------------------------------
// prep: weight-cast (blocks 0..2047) + LayerNorm q/k/v (2048..8191) +
// zero atomic accumulators (8192..8204) -- no host memset needed.
// ---------------------------------------------------------------------------
__global__ __launch_bounds__(256) void prep(const float* __restrict__ q,
                                            const float* __restrict__ k,
                                            const float* __restrict__ v,
                                            const float* __restrict__ g,
                                            const float* __restrict__ b,
                                            u16* __restrict__ out,
                                            const float* __restrict__ w_in,
                                            const float* __restrict__ w_out,
                                            u16* __restrict__ w_in16,
                                            u16* __restrict__ w_out16,
                                            float* __restrict__ zbuf) {
    const int bb = blockIdx.x;
    const int tid = threadIdx.x;
    if (bb >= 8192) {
        int idx = (bb - 8192) * 256 + tid;
        if (idx < 3 * H * D + H) zbuf[idx] = 0.0f;
        return;
    }
    if (bb < 2048) {
        const int n4each = DIM * DIM / 4;
        int i = bb * 256 + tid;
        const float* src; u16* dst; int j;
        if (i < n4each) { src = w_in;  dst = w_in16;  j = i; }
        else            { src = w_out; dst = w_out16; j = i - n4each; }
        float4 vv = *(const float4*)(src + (size_t)j * 4);
        ushort4 pk;
        pk.x = f2b(vv.x); pk.y = f2b(vv.y); pk.z = f2b(vv.z); pk.w = f2b(vv.w);
        *(ushort4*)(dst + (size_t)j * 4) = pk;
        return;
    }
    const int b2 = bb - 2048;                    // 0..6143
    const int wv = tid >> 6, lane = tid & 63;
    const int row = b2 * 4 + wv;                 // 0..24575
    const int y = row >> 13, r = row & 8191;
    const float* src = (y == 0) ? q : (y == 1) ? k : v;
    const float* rp = src + (size_t)r * DIM;
    float4 x0 = *(const float4*)(rp + (0 * 64 + lane) * 4);
    float4 x1 = *(const float4*)(rp + (1 * 64 + lane) * 4);
    float4 x2 = *(const float4*)(rp + (2 * 64 + lane) * 4);
    float4 x3 = *(const float4*)(rp + (3 * 64 + lane) * 4);
    float sum = (x0.x + x0.y + x0.z + x0.w) + (x1.x + x1.y + x1.z + x1.w)
              + (x2.x + x2.y + x2.z + x2.w) + (x3.x + x3.y + x3.z + x3.w);
    float sq = x0.x*x0.x + x0.y*x0.y + x0.z*x0.z + x0.w*x0.w
             + x1.x*x1.x + x1.y*x1.y + x1.z*x1.z + x1.w*x1.w
             + x2.x*x2.x + x2.y*x2.y + x2.z*x2.z + x2.w*x2.w
             + x3.x*x3.x + x3.y*x3.y + x3.z*x3.z + x3.w*x3.w;
#pragma unroll
    for (int o = 32; o > 0; o >>= 1) {
        sum += __shfl_xor(sum, o);
        sq  += __shfl_xor(sq, o);
    }
    float mean = sum * (1.0f / DIM);
    float var = sq * (1.0f / DIM) - mean * mean;
    float rstd = rsqrtf(var + 1e-5f);
    u16* op = out + ((size_t)y * R + r) * DIM;
    float4 xs[4] = {x0, x1, x2, x3};
#pragma unroll
    for (int p = 0; p < 4; p++) {
        int e4 = (p * 64 + lane) * 4;
        float4 gv = *(const float4*)(g + e4);
        float4 bv = *(const float4*)(b + e4);
        ushort4 pk;
        pk.x = f2b((xs[p].x - mean) * rstd * gv.x + bv.x);
        pk.y = f2b((xs[p].y - mean) * rstd * gv.y + bv.y);
        pk.z = f2b((xs[p].z - mean) * rstd * gv.z + bv.z);
        pk.w = f2b((xs[p].w - mean) * rstd * gv.w + bv.w);
        *(ushort4*)(op + e4) = pk;
    }
}

// ---------------------------------------------------------------------------
// Stacked QKV projection, operand-SWAPPED MFMA, BK=64.  Column-fold epilogue
// computes qg/ubuf/s2 (seg 0) and kg (seg 1) block-partials from the live
// accumulator and atomicAdds into zeroed buffers -- removes the colsum
// third of fanout.  j-sequential to bound register pressure.
// ---------------------------------------------------------------------------
__global__ __launch_bounds__(256) void gemm_qkv(const u16* __restrict__ A,
                                                const u16* __restrict__ B,
                                                u16* __restrict__ qT,
                                                u16* __restrict__ fqb,
                                                u16* __restrict__ kTh,
                                                u16* __restrict__ vT,
                                                float* __restrict__ qn,
                                                float* __restrict__ qr,
                                                float* __restrict__ kn,
                                                float* __restrict__ kr,
                                                float* __restrict__ qg,
                                                float* __restrict__ kg,
                                                float* __restrict__ ubuf,
                                                float* __restrict__ s2g) {
    __shared__ __align__(16) u16 smem[19712];
    u16* As  = smem;                             // 4096 u16 (k lo)
    u16* Bs  = smem + 4096;                      // 4096 u16 (k lo)
    u16* As2 = smem + 8192;                      // 4096 u16 (k hi)
    u16* Bs2 = smem + 12288;                     // 4096 u16 (k hi)
    float* sred = (float*)(smem + 18432);        // 128*4 floats
    float* invb = (float*)(smem + 19456);        // 128 floats

    const int tid = threadIdx.x;
    const int bb = blockIdx.x;
    const int xcd = bb & 7, j0 = bb >> 3;
    const int h = j0 & 7;                        // column block (head)
    const int rowblk = xcd * 24 + (j0 >> 3);     // 0..191
    const int m0 = rowblk * 128, n0 = h * 128;
    const int seg = rowblk >> 6;                 // 0=Q 1=K 2=V
    const int lrb = (rowblk & 63) * 128;         // segment-local row base

    const int wave = tid >> 6, lane = tid & 63;
    const int wm = (wave >> 1) * 64, wn = (wave & 1) * 64;
    const int fr = lane & 15, kq = lane >> 4;
    const int srow = tid >> 2, scol = (tid & 3) * 8;

    floatx4 acc[4][4] = {};                      // [j=c-tile][i=r-tile]
    const size_t aOff0 = (size_t)(m0 + srow) * DIM + scol;
    const size_t aOff1 = (size_t)(m0 + 64 + srow) * DIM + scol;
    const size_t bOff0 = (size_t)(n0 + srow) * DIM + scol;
    const size_t bOff1 = (size_t)(n0 + 64 + srow) * DIM + scol;

    for (int kt = 0; kt < DIM; kt += 64) {
        GLOAD_LDS16(A + aOff0 + kt, As + tid * 8);
        GLOAD_LDS16(A + aOff1 + kt, As + (256 + tid) * 8);
        GLOAD_LDS16(B + bOff0 + kt, Bs + tid * 8);
        GLOAD_LDS16(B + bOff1 + kt, Bs + (256 + tid) * 8);
        GLOAD_LDS16(A + aOff0 + kt + 32, As2 + tid * 8);
        GLOAD_LDS16(A + aOff1 + kt + 32, As2 + (256 + tid) * 8);
        GLOAD_LDS16(B + bOff0 + kt + 32, Bs2 + tid * 8);
        GLOAD_LDS16(B + bOff1 + kt + 32, Bs2 + (256 + tid) * 8);
        __syncthreads();
        short8 xf[4], wf[4];
#pragma unroll
        for (int i = 0; i < 4; i++)
            xf[i] = *(const short8*)&As[(wm + i * 16 + fr) * 32 + kq * 8];
#pragma unroll
        for (int j = 0; j < 4; j++)
            wf[j] = *(const short8*)&Bs[(wn + j * 16 + fr) * 32 + kq * 8];
#pragma unroll
        for (int j = 0; j < 4; j++)
#pragma unroll
            for (int i = 0; i < 4; i++)
                acc[j][i] = __builtin_amdgcn_mfma_f32_16x16x32_bf16(wf[j], xf[i], acc[j][i], 0, 0, 0);
        short8 xg[4], wg[4];
#pragma unroll
        for (int i = 0; i < 4; i++)
            xg[i] = *(const short8*)&As2[(wm + i * 16 + fr) * 32 + kq * 8];
#pragma unroll
        for (int j = 0; j < 4; j++)
            wg[j] = *(const short8*)&Bs2[(wn + j * 16 + fr) * 32 + kq * 8];
#pragma unroll
        for (int j = 0; j < 4; j++)
#pragma unroll
            for (int i = 0; i < 4; i++)
                acc[j][i] = __builtin_amdgcn_mfma_f32_16x16x32_bf16(wg[j], xg[i], acc[j][i], 0, 0, 0);
        __syncthreads();
    }

    // ---- per-row stats: lane holds rows r = wm+i*16+fr, cols c = wn+j*16+kq*4+reg
    if (seg <= 1) {
        const int half = wn >> 6;
#pragma unroll
        for (int i = 0; i < 4; i++) {
            float s = 0.0f, qs = 0.0f;
#pragma unroll
            for (int j = 0; j < 4; j++)
#pragma unroll
                for (int rg = 0; rg < 4; rg++) {
                    float vv = acc[j][i][rg];
                    s += vv; qs += vv * vv;
                }
            s += __shfl_xor(s, 16); qs += __shfl_xor(qs, 16);
            s += __shfl_xor(s, 32); qs += __shfl_xor(qs, 32);
            if (kq == 0) {
                int rl = wm + i * 16 + fr;
                sred[rl * 4 + half * 2 + 0] = s;
                sred[rl * 4 + half * 2 + 1] = qs;
            }
        }
        __syncthreads();
        if (tid < 128) {
            float sum = sred[tid * 4 + 0] + sred[tid * 4 + 2];
            float sq  = sred[tid * 4 + 1] + sred[tid * 4 + 3];
            float nrm = sqrtf(sq);
            float var = (sq - sum * sum * (1.0f / D)) * (1.0f / (D - 1));
            float ratio = 2.0f * fminf(var, 1.0f) / (var + 1.0f);
            size_t idx = (size_t)h * R + lrb + tid;
            if (seg == 0) {
                qn[idx] = nrm; qr[idx] = ratio;
            } else {
                kn[idx] = nrm; kr[idx] = ratio;
                invb[tid] = 1.0f / nrm;
            }
        }
        __syncthreads();

        // ---- column-fold: block-partial col sums -> atomics (was colsum)
        float* colg = (float*)(smem + 8192);     // 256 floats (As2 region)
        float* colu = (float*)(smem + 8704);     // 256 floats
        for (int j = 0; j < 4; j++) {            // sequential: low reg pressure
            float cg[4] = {0, 0, 0, 0};
            float cu[4] = {0, 0, 0, 0};
#pragma unroll
            for (int i = 0; i < 4; i++) {
                int rl = wm + i * 16 + fr;
                float qmv = (sred[rl * 4 + 0] + sred[rl * 4 + 2]) * (1.0f / D);
#pragma unroll
                for (int rg = 0; rg < 4; rg++) {
                    float vv = acc[j][i][rg];
                    cg[rg] += vv;
                    cu[rg] += qmv * vv;
                }
            }
#pragma unroll
            for (int o = 1; o < 16; o <<= 1) {
#pragma unroll
                for (int rg = 0; rg < 4; rg++) {
                    cg[rg] += __shfl_xor(cg[rg], o);
                    cu[rg] += __shfl_xor(cu[rg], o);
                }
            }
            if (fr == 0) {
#pragma unroll
                for (int rg = 0; rg < 4; rg++) {
                    int c = wn + j * 16 + kq * 4 + rg;
                    colg[c * 2 + (wm >> 6)] = cg[rg];
                    colu[c * 2 + (wm >> 6)] = cu[rg];
                }
            }
        }
        __syncthreads();
        if (tid < 128) {
            float vg = colg[tid * 2] + colg[tid * 2 + 1];
            if (seg == 0) {
                atomicAdd(&qg[h * D + tid], vg);
                atomicAdd(&ubuf[h * D + tid], colu[tid * 2] + colu[tid * 2 + 1]);
            } else {
                atomicAdd(&kg[h * D + tid], vg);
            }
        }
        if (seg == 0) {
            float q2 = 0.0f;
            if (tid < 128) {
                float qmv = (sred[tid * 4 + 0] + sred[tid * 4 + 2]) * (1.0f / D);
                q2 = qmv * qmv;
            }
#pragma unroll
            for (int o = 32; o > 0; o >>= 1) q2 += __shfl_xor(q2, o);
            if ((tid & 63) == 0) invb[tid >> 6] = q2;   // invb free in seg 0
            __syncthreads();
            if (tid == 0)
                atomicAdd(&s2g[h], invb[0] + invb[1] + invb[2] + invb[3]);
        }
        __syncthreads();
    }

    // ---- transposed store: qT/kTh/vT [h][c][r] -- 16-lane r-contiguous
    u16* dstT = (seg == 0) ? qT : (seg == 1) ? kTh : vT;
#pragma unroll
    for (int i = 0; i < 4; i++) {
        const int rl = wm + i * 16 + fr;
        const float sc = (seg == 1) ? invb[rl] : 1.0f;
#pragma unroll
        for (int j = 0; j < 4; j++) {
#pragma unroll
            for (int rg = 0; rg < 4; rg++) {
                const int cl = wn + j * 16 + kq * 4 + rg;
                dstT[(size_t)(h * D + cl) * R + lrb + rl] = f2b(acc[j][i][rg] * sc);
            }
        }
    }

    // ---- seg 0: fqb row-major via padded LDS transpose (coalesced 128B rows)
    if (seg == 0) {
        __syncthreads();
        u16* Tw = smem + wave * 4608;            // 64 x 72 u16
#pragma unroll
        for (int i = 0; i < 4; i++)
#pragma unroll
            for (int j = 0; j < 4; j++) {
                ushort4 pk;
                pk.x = f2b(acc[j][i][0]); pk.y = f2b(acc[j][i][1]);
                pk.z = f2b(acc[j][i][2]); pk.w = f2b(acc[j][i][3]);
                *(ushort4*)&Tw[(i * 16 + fr) * 72 + j * 16 + kq * 4] = pk;
            }
        __syncthreads();
#pragma unroll
        for (int p = 0; p < 16; p++) {
            int rloc = p * 4 + kq;
            int c4 = fr * 4;
            ushort4 v = *(const ushort4*)&Tw[rloc * 72 + c4];
            *(ushort4*)&fqb[(size_t)(lrb + wm + rloc) * DIM + h * D + wn + c4] = v;
        }
    }
}

// ---------------------------------------------------------------------------
// fanout: fused  ktv_mfma (blocks 0..127, BK=64)  |  syrk_q (128..191, BK=64)
// colsum now folded into gemm_qkv -> 192 blocks, all co-resident.
// ---------------------------------------------------------------------------
__global__ __launch_bounds__(256) void fanout(const u16* __restrict__ qT,
                                              const u16* __restrict__ kTh,
                                              const u16* __restrict__ vT,
                                              const float* __restrict__ kr,
                                              float* __restrict__ P,
                                              u16* __restrict__ Mt,
                                              float* __restrict__ sv) {
    __shared__ __align__(16) u16 sm[17040];      // 34080 B
    u16* As = sm;                                // 8192 u16 (2 chunks x 4096)
    u16* Bs = sm + 8192;                         // 8192 u16
    float* wbuf  = (float*)(sm + 16384);         // 64 floats
    float* svred = (float*)(sm + 16512);         // 256 floats

    const int bb = blockIdx.x;
    const int tid = threadIdx.x;
    const int wave = tid >> 6, lane = tid & 63;
    const int wm = (wave >> 1) * 64, wn = (wave & 1) * 64;
    const int fr = lane & 15, kq = lane >> 4;
    const int srow = tid >> 2, scol = (tid & 3) * 8;

    if (bb < 128) {
        const int qi = bb & 15, h = bb >> 4;
        const int m0g = qi * 512;
        const size_t a0 = (size_t)(h * D + srow) * R + m0g + scol;
        const size_t a1 = (size_t)(h * D + 64 + srow) * R + m0g + scol;
        const int e_id = tid & 127, mb16 = (tid >> 7) * 16;
        float svacc = 0.0f;
        floatx4 acc[4][4] = {};
        for (int kt = 0; kt < 512; kt += 64) {
#pragma unroll
            for (int kc = 0; kc < 2; kc++) {
                GLOAD_LDS16(vT + a0 + kt + kc * 32, As + kc * 4096 + tid * 8);
                GLOAD_LDS16(vT + a1 + kt + kc * 32, As + kc * 4096 + (256 + tid) * 8);
                GLOAD_LDS16(kTh + a0 + kt + kc * 32, Bs + kc * 4096 + tid * 8);
                GLOAD_LDS16(kTh + a1 + kt + kc * 32, Bs + kc * 4096 + (256 + tid) * 8);
            }
            if (tid < 64) wbuf[tid] = kr[(size_t)h * R + m0g + kt + tid];
            __syncthreads();
#pragma unroll
            for (int kc = 0; kc < 2; kc++) {
                short8 af[4], bf[4];
#pragma unroll
                for (int i = 0; i < 4; i++)
                    af[i] = *(const short8*)&As[kc * 4096 + (wm + i * 16 + fr) * 32 + kq * 8];
#pragma unroll
                for (int j = 0; j < 4; j++)
                    bf[j] = *(const short8*)&Bs[kc * 4096 + (wn + j * 16 + fr) * 32 + kq * 8];
#pragma unroll
                for (int i = 0; i < 4; i++)
#pragma unroll
                    for (int j = 0; j < 4; j++)
                        acc[i][j] = __builtin_amdgcn_mfma_f32_16x16x32_bf16(af[i], bf[j], acc[i][j], 0, 0, 0);
                short8 va = *(const short8*)&As[kc * 4096 + e_id * 32 + mb16];
                short8 vb = *(const short8*)&As[kc * 4096 + e_id * 32 + mb16 + 8];
#pragma unroll
                for (int jm = 0; jm < 8; jm++)
                    svacc += b2f((u16)va[jm]) * wbuf[kc * 32 + mb16 + jm];
#pragma unroll
                for (int jm = 0; jm < 8; jm++)
                    svacc += b2f((u16)vb[jm]) * wbuf[kc * 32 + mb16 + 8 + jm];
            }
            __syncthreads();
        }
        u16* mb = Mt + (size_t)(h * QB + qi) * D * D;
#pragma unroll
        for (int i = 0; i < 4; i++) {
            int er = wm + i * 16 + kq * 4;
#pragma unroll
            for (int j = 0; j < 4; j++) {
                int dc = wn + j * 16 + fr;
#pragma unroll
                for (int r = 0; r < 4; r++)
                    mb[(size_t)(er + r) * D + dc] = f2b(acc[i][j][r]);
            }
        }
        svred[tid] = svacc;
        __syncthreads();
        if (tid < 128)
            sv[(size_t)(h * QB + qi) * D + tid] = svred[tid] + svred[tid + 128];
    } else {
        const int t = bb - 128;
        const int c = t & 7, h = t >> 3;
        floatx4 acc[4][4] = {};
        const size_t a0 = (size_t)(h * D + srow) * R + c * 1024 + scol;
        const size_t a1 = (size_t)(h * D + 64 + srow) * R + c * 1024 + scol;
        for (int kt = 0; kt < 1024; kt += 64) {
#pragma unroll
            for (int kc = 0; kc < 2; kc++) {
                GLOAD_LDS16(qT + a0 + kt + kc * 32, As + kc * 4096 + tid * 8);
                GLOAD_LDS16(qT + a1 + kt + kc * 32, As + kc * 4096 + (256 + tid) * 8);
            }
            __syncthreads();
#pragma unroll
            for (int kc = 0; kc < 2; kc++) {
                short8 af[4], bf[4];
#pragma unroll
                for (int i = 0; i < 4; i++)
                    af[i] = *(const short8*)&As[kc * 4096 + (wm + i * 16 + fr) * 32 + kq * 8];
#pragma unroll
                for (int j = 0; j < 4; j++)
                    bf[j] = *(const short8*)&As[kc * 4096 + (wn + j * 16 + fr) * 32 + kq * 8];
#pragma unroll
                for (int i = 0; i < 4; i++)
#pragma unroll
                    for (int j = 0; j < 4; j++)
                        acc[i][j] = __builtin_amdgcn_mfma_f32_16x16x32_bf16(af[i], bf[j], acc[i][j], 0, 0, 0);
            }
            __syncthreads();
        }
        float* base = P + (size_t)(h * 8 + c) * (D * D);
#pragma unroll
        for (int i = 0; i < 4; i++) {
            int dr = wm + i * 16 + kq * 4;
#pragma unroll
            for (int j = 0; j < 4; j++) {
                int ec = wn + j * 16 + fr;
                float4 f4;
                f4.x = acc[i][j][0]; f4.y = acc[i][j][1];
                f4.z = acc[i][j][2]; f4.w = acc[i][j][3];
                *(float4*)&base[(size_t)ec * D + dr] = f4;   // symmetric chunk
            }
        }
    }
}

// ---------------------------------------------------------------------------
// Reduce 8 syrk partials + centering + off-diag Frobenius partial per block.
// grid (64, H): Spart[h*64 + bx]  (full chip fill)
// ---------------------------------------------------------------------------
__global__ __launch_bounds__(256) void decorr_sum(const float* __restrict__ P,
                                                  const float* __restrict__ ubuf,
                                                  const float* __restrict__ s2b,
                                                  float* __restrict__ Spart) {
    int bx = blockIdx.x, h = blockIdx.y, tid = threadIdx.x;
    float s2h = s2b[h];
    int de = bx * 256 + tid;
    int dd = de >> 7, ee = de & 127;
    float g = 0.0f;
#pragma unroll
    for (int c = 0; c < 8; c++)
        g += P[(size_t)(h * 8 + c) * (D * D) + de];
    float S = 0.0f;
    if (dd != ee) {
        float vv = (g - ubuf[h * D + dd] - ubuf[h * D + ee] + s2h) * (1.0f / R);
        S = vv * vv;
    }
#pragma unroll
    for (int o = 32; o > 0; o >>= 1) S += __shfl_xor(S, o);
    __shared__ float r1[4];
    if ((tid & 63) == 0) r1[tid >> 6] = S;
    __syncthreads();
    if (tid == 0) Spart[h * 64 + bx] = r1[0] + r1[1] + r1[2] + r1[3];
}

// ---------------------------------------------------------------------------
// Per-head: dscale from Spart + predictor MLP -> coef.  qg/kg are RAW column
// sums from gemm_qkv atomics -> scale by 1/R here.
// ---------------------------------------------------------------------------
__global__ __launch_bounds__(256) void head_kernel(const float* __restrict__ Spart,
                                                   const float* __restrict__ qg,
                                                   const float* __restrict__ kg,
                                                   const float* __restrict__ w1,
                                                   const float* __restrict__ b1,
                                                   const float* __restrict__ lng,
                                                   const float* __restrict__ lnb,
                                                   const float* __restrict__ w2,
                                                   const float* __restrict__ b2,
                                                   float* __restrict__ coef) {
    int h = blockIdx.x, tid = threadIdx.x;
    __shared__ float s1[256], s2[256], s3[256];
    __shared__ float feats[256];
    float Ssum = 0.0f;
    for (int c = 0; c < 64; c++) Ssum += Spart[h * 64 + c];
    float dscale = expf(-5.0f * sqrtf(Ssum) / (float)(D * D));
    feats[tid] = ((tid < 128) ? qg[h * D + tid] : kg[h * D + tid - 128]) * (1.0f / R);
    __syncthreads();
    float yv = 0.0f;
    if (tid < 128) {
        float a = b1[tid];
        for (int i = 0; i < 256; i++) a = fmaf(feats[i], w1[tid * 256 + i], a);
        yv = a;
    }
    s1[tid] = (tid < 128) ? yv : 0.0f;
    s2[tid] = (tid < 128) ? yv * yv : 0.0f;
    __syncthreads();
    for (int s = 128; s > 0; s >>= 1) {
        if (tid < s) { s1[tid] += s1[tid + s]; s2[tid] += s2[tid + s]; }
        __syncthreads();
    }
    float mean = s1[0] * (1.0f / 128.0f);
    float var = s2[0] * (1.0f / 128.0f) - mean * mean;
    float rstd = rsqrtf(var + 1e-5f);
    float rel = 0.0f;
    if (tid < 128)
        rel = fmaxf((yv - mean) * rstd * lng[tid] + lnb[tid], 0.0f);
    __syncthreads();
    s1[tid] = (tid < 128) ? rel * w2[0 * 128 + tid] : 0.0f;
    s2[tid] = (tid < 128) ? rel * w2[1 * 128 + tid] : 0.0f;
    s3[tid] = (tid < 128) ? rel * w2[2 * 128 + tid] : 0.0f;
    __syncthreads();
    for (int s = 128; s > 0; s >>= 1) {
        if (tid < s) { s1[tid] += s1[tid + s]; s2[tid] += s2[tid + s]; s3[tid] += s3[tid + s]; }
        __syncthreads();
    }
    if (tid == 0) {
        float g0 = s1[0] + b2[0], g1 = s2[0] + b2[1], g2 = s3[0] + b2[2];
        float mx = fmaxf(g0, fmaxf(g1, g2));
        float e0 = expf(g0 - mx), e1 = expf(g1 - mx), e2 = expf(g2 - mx);
        float inv = 1.0f / (e0 + e1 + e2);
        coef[h * 2 + 0] = e0 * inv + e1 * inv * dscale;  // cw + vw*decorr_scale
        coef[h * 2 + 1] = e2 * inv;                      // ww
    }
}

// ---------------------------------------------------------------------------
// attn: out[n,e] = sc1[n]*(sum_d fq[n,d]*Mt[e,d]) + sc2[n]*sv[e]  -> bf16
// K=128 fits entirely in LDS: one-shot staging, ONE barrier.  (R5 verbatim)
// ---------------------------------------------------------------------------
__global__ __launch_bounds__(256) void attn_mfma(const u16* __restrict__ fqb,
                                                 const u16* __restrict__ Mt,
                                                 const float* __restrict__ qn,
                                                 const float* __restrict__ qr,
                                                 const float* __restrict__ sv,
                                                 const float* __restrict__ coef,
                                                 u16* __restrict__ outb) {
    __shared__ u16 As[128 * 128];    // 32 KB: 4 chunks of [128][32]
    __shared__ u16 Bs[128 * 128];    // 32 KB
    const int nb = blockIdx.x, qi = blockIdx.y, h = blockIdx.z;
    const int tid = threadIdx.x;
    const int wave = tid >> 6, lane = tid & 63;
    const int wm = (wave >> 1) * 64, wn = (wave & 1) * 64;
    const int fr = lane & 15, kq = lane >> 4;
    const int srow = tid >> 2, scol = (tid & 3) * 8;
    const int n0g = qi * 512 + nb * 128;
    const size_t a0 = (size_t)(n0g + srow) * DIM + h * D + scol;
    const size_t a1 = (size_t)(n0g + 64 + srow) * DIM + h * D + scol;
    const u16* mtb = Mt + (size_t)(h * QB + qi) * D * D;
#pragma unroll
    for (int kc = 0; kc < 4; kc++) {
        GLOAD_LDS16(fqb + a0 + kc * 32, As + kc * 4096 + tid * 8);
        GLOAD_LDS16(fqb + a1 + kc * 32, As + kc * 4096 + (256 + tid) * 8);
        GLOAD_LDS16(mtb + (size_t)srow * D + kc * 32 + scol, Bs + kc * 4096 + tid * 8);
        GLOAD_LDS16(mtb + (size_t)(64 + srow) * D + kc * 32 + scol, Bs + kc * 4096 + (256 + tid) * 8);
    }
    __syncthreads();
    floatx4 acc[4][4] = {};
#pragma unroll
    for (int kc = 0; kc < 4; kc++) {
        short8 af[4], bf[4];
#pragma unroll
        for (int i = 0; i < 4; i++)
            af[i] = *(const short8*)&As[kc * 4096 + (wm + i * 16 + fr) * 32 + kq * 8];
#pragma unroll
        for (int j = 0; j < 4; j++)
            bf[j] = *(const short8*)&Bs[kc * 4096 + (wn + j * 16 + fr) * 32 + kq * 8];
#pragma unroll
        for (int i = 0; i < 4; i++)
#pragma unroll
            for (int j = 0; j < 4; j++)
                acc[i][j] = __builtin_amdgcn_mfma_f32_16x16x32_bf16(af[i], bf[j], acc[i][j], 0, 0, 0);
    }
    float c0 = coef[2 * h], c1 = coef[2 * h + 1];
#pragma unroll
    for (int i = 0; i < 4; i++) {
        int nr = n0g + wm + i * 16 + kq * 4;
        float4 nv = *(const float4*)&qn[(size_t)h * R + nr];
        float4 rv = *(const float4*)&qr[(size_t)h * R + nr];
        float sc1[4] = {c0 / nv.x, c0 / nv.y, c0 / nv.z, c0 / nv.w};
        float sc2[4] = {c1 * rv.x, c1 * rv.y, c1 * rv.z, c1 * rv.w};
#pragma unroll
        for (int j = 0; j < 4; j++) {
            int ec = wn + j * 16 + fr;
            float svv = sv[(size_t)(h * QB + qi) * D + ec];
#pragma unroll
            for (int r = 0; r < 4; r++)
                outb[(size_t)(nr + r) * DIM + h * D + ec] = f2b(sc1[r] * acc[i][j][r] + sc2[r] * svv);
        }
    }
}

// ---------------------------------------------------------------------------
// Output GEMM, 1-D grid 512 with XCD swizzle, BK=64.  (verbatim, proven)
// ---------------------------------------------------------------------------
__global__ __launch_bounds__(256) void gemm_out(const u16* __restrict__ A,
                                                const u16* __restrict__ B,
                                                const float* __restrict__ bias,
                                                float* __restrict__ C) {
    __shared__ u16 As[128 * 64];
    __shared__ u16 Bs[128 * 64];
    const int tid = threadIdx.x;
    const int bb = blockIdx.x;
    const int xcd = bb & 7, jj = bb >> 3;
    const int col = jj & 7, rowblk = xcd * 8 + (jj >> 3);
    const int m0 = rowblk * 128, n0 = col * 128;
    const int wave = tid >> 6, lane = tid & 63;
    const int wm = (wave >> 1) * 64, wn = (wave & 1) * 64;
    const int fr = lane & 15, kq = lane >> 4;
    const int srow = tid >> 2, scol = (tid & 3) * 8;
    floatx4 acc[4][4] = {};
    const size_t aOff0 = (size_t)(m0 + srow) * DIM + scol;
    const size_t aOff1 = (size_t)(m0 + 64 + srow) * DIM + scol;
    const size_t bOff0 = (size_t)(n0 + srow) * DIM + scol;
    const size_t bOff1 = (size_t)(n0 + 64 + srow) * DIM + scol;
    for (int kt = 0; kt < DIM; kt += 64) {
        GLOAD_LDS16(A + aOff0 + kt, As + tid * 8);
        GLOAD_LDS16(A + aOff1 + kt, As + (256 + tid) * 8);
        GLOAD_LDS16(A + aOff0 + kt + 32, As + (512 + tid) * 8);
        GLOAD_LDS16(A + aOff1 + kt + 32, As + (768 + tid) * 8);
        GLOAD_LDS16(B + bOff0 + kt, Bs + tid * 8);
        GLOAD_LDS16(B + bOff1 + kt, Bs + (256 + tid) * 8);
        GLOAD_LDS16(B + bOff0 + kt + 32, Bs + (512 + tid) * 8);
        GLOAD_LDS16(B + bOff1 + kt + 32, Bs + (768 + tid) * 8);
        __syncthreads();
        short8 af[4], bf[4];
#pragma unroll
        for (int i = 0; i < 4; i++)
            af[i] = *(const short8*)&As[(wm + i * 16 + fr) * 32 + kq * 8];
#pragma unroll
        for (int j = 0; j < 4; j++)
            bf[j] = *(const short8*)&Bs[(wn + j * 16 + fr) * 32 + kq * 8];
#pragma unroll
        for (int i = 0; i < 4; i++)
#pragma unroll
            for (int j = 0; j < 4; j++)
                acc[i][j] = __builtin_amdgcn_mfma_f32_16x16x32_bf16(af[i], bf[j], acc[i][j], 0, 0, 0);
        short8 ag[4], bg[4];
#pragma unroll
        for (int i = 0; i < 4; i++)
            ag[i] = *(const short8*)&As[4096 + (wm + i * 16 + fr) * 32 + kq * 8];
#pragma unroll
        for (int j = 0; j < 4; j++)
            bg[j] = *(const short8*)&Bs[4096 + (wn + j * 16 + fr) * 32 + kq * 8];
#pragma unroll
        for (int i = 0; i < 4; i++)
#pragma unroll
            for (int j = 0; j < 4; j++)
                acc[i][j] = __builtin_amdgcn_mfma_f32_16x16x32_bf16(ag[i], bg[j], acc[i][j], 0, 0, 0);
        __syncthreads();
    }
#pragma unroll
    for (int i = 0; i < 4; i++) {
        int rbase = m0 + wm + i * 16 + kq * 4;
#pragma unroll
        for (int j = 0; j < 4; j++) {
            int c = n0 + wn + j * 16 + fr;
            float badd = bias[c];
#pragma unroll
            for (int r = 0; r < 4; r++)
                C[(size_t)(rbase + r) * DIM + c] = acc[i][j][r] + badd;
        }
    }
}

// ---------------------------------------------------------------------------
extern "C" void kernel_launch(void* const* d_in, const int* in_sizes, int n_in,
                              void* d_out, int out_size, void* d_ws, size_t ws_size,
                              hipStream_t stream) {
    (void)in_sizes; (void)n_in; (void)out_size; (void)ws_size;
    const float* q      = (const float*)d_in[0];
    const float* k      = (const float*)d_in[1];
    const float* v      = (const float*)d_in[2];
    const float* ln_g   = (const float*)d_in[3];
    const float* ln_b   = (const float*)d_in[4];
    const float* w_in   = (const float*)d_in[5];
    const float* wp_w1  = (const float*)d_in[6];
    const float* wp_b1  = (const float*)d_in[7];
    const float* wp_lng = (const float*)d_in[8];
    const float* wp_lnb = (const float*)d_in[9];
    const float* wp_w2  = (const float*)d_in[10];
    const float* wp_b2  = (const float*)d_in[11];
    const float* w_out  = (const float*)d_in[12];
    const float* b_out  = (const float*)d_in[13];
    float* out = (float*)d_out;

    constexpr size_t F = (size_t)R * DIM;     // 8,388,608 elements
    u16* lnall   = (u16*)d_ws;                // 3F (LN out; first F reused as attn out)
    u16* fqb     = lnall + 3 * F;             // f_q row-major bf16
    u16* qT      = fqb + F;                   // [h][d][r]
    u16* kTh     = qT + F;                    // K/||k||
    u16* vT      = kTh + F;                   // V (plain)
    u16* w_in16  = vT + F;
    u16* w_out16 = w_in16 + (size_t)DIM * DIM;
    u16* Mt      = w_out16 + (size_t)DIM * DIM;       // H*QB*D*D
    float* P     = (float*)(Mt + (size_t)H * QB * D * D);  // 8*H*D*D fp32 used
    float* qn    = P + (size_t)32 * H * D * D;
    float* qm    = qn + (size_t)H * R;        // buffer reused for Spart
    float* qr    = qm + (size_t)H * R;
    float* kn    = qr + (size_t)H * R;
    float* kr    = kn + (size_t)H * R;
    float* qg    = kr + (size_t)H * R;        // H*D  (atomic-accumulated, raw)
    float* kg    = qg + H * D;                // H*D  (atomic-accumulated, raw)
    float* ubuf  = kg + H * D;                // H*D  (atomic-accumulated, raw)
    float* s2    = ubuf + H * D;              // H    (atomic-accumulated)
    float* Spart = s2 + H;                    // (legacy slot, unused)
    float* coef  = Spart + H * 8;             // 16
    float* svb   = coef + 16;                 // H*QB*D
    float* SpartN = qm;                       // H*64 floats

    // prep grid: 2048 cast + 6144 LN + 13 zero-blocks (qg..s2 = 3080 floats)
    prep<<<8205, 256, 0, stream>>>(q, k, v, ln_g, ln_b, lnall,
                                   w_in, w_out, w_in16, w_out16, qg);

    gemm_qkv<<<1536, 256, 0, stream>>>(lnall, w_in16, qT, fqb, kTh, vT,
                                       qn, qr, kn, kr, qg, kg, ubuf, s2);

    fanout<<<192, 256, 0, stream>>>(qT, kTh, vT, kr, P, Mt, svb);

    decorr_sum<<<dim3(64, H), 256, 0, stream>>>(P, ubuf, s2, SpartN);

    head_kernel<<<H, 256, 0, stream>>>(SpartN, qg, kg, wp_w1, wp_b1,
                                       wp_lng, wp_lnb, wp_w2, wp_b2, coef);

    attn_mfma<<<dim3(4, QB, H), 256, 0, stream>>>(fqb, Mt, qn, qr, svb, coef, lnall);

    gemm_out<<<512, 256, 0, stream>>>(lnall, w_out16, b_out, out);
}